// Round 1
// baseline (786.751 us; speedup 1.0000x reference)
//
#include <hip/hip_runtime.h>

// WaveletConv2D: 2-level DWT (8-tap), per-position 64x64 channel mix on the
// 4 level-2 subbands, then 2-level inverse DWT. All fp32.
// Shapes: x (32,128,128,64) NHWC; weights (64,64,32,32) iohw; out (32,128,128,64).

__constant__ float c_h0[8] = {0.0322231f, -0.01260397f, -0.09921954f, 0.2978578f,
                              0.80373875f, 0.49761867f, -0.02963553f, -0.07576571f};
__constant__ float c_h1[8] = {0.07576571f, -0.02963553f, -0.49761867f, 0.80373875f,
                              -0.2978578f, -0.09921954f, 0.01260397f, 0.0322231f};
// g0 = reverse(h0), g1 = reverse(h1)
__constant__ float c_g0[8] = {-0.07576571f, -0.02963553f, 0.49761867f, 0.80373875f,
                              0.2978578f, -0.09921954f, -0.01260397f, 0.0322231f};
__constant__ float c_g1[8] = {0.0322231f, 0.01260397f, -0.09921954f, -0.2978578f,
                              0.80373875f, -0.49761867f, -0.02963553f, 0.07576571f};

// ---- Stage 1: x (32,128,128,64) -> ll1 (32,64,64,64), h0 x h0, stride 2, pad 3 ----
__global__ __launch_bounds__(256) void k_dwt1(const float* __restrict__ x,
                                              float* __restrict__ ll1) {
  int tid = blockIdx.x * 256 + threadIdx.x;
  int c  = tid & 63;
  int ow = (tid >> 6) & 63;
  int oh = (tid >> 12) & 63;
  int b  = tid >> 18;
  const float* xb = x + ((size_t)b << 20) + c;  // b*128*128*64
  float acc = 0.f;
#pragma unroll
  for (int i = 0; i < 8; ++i) {
    int ih = 2 * oh - 3 + i;
    if ((unsigned)ih < 128u) {
      const float* row = xb + ih * (128 * 64);
      float r = 0.f;
#pragma unroll
      for (int j = 0; j < 8; ++j) {
        int iw = 2 * ow - 3 + j;
        if ((unsigned)iw < 128u) r += c_h0[j] * row[iw << 6];
      }
      acc += c_h0[i] * r;
    }
  }
  ll1[tid] = acc;
}

// ---- Stage 2: ll1 (32,64,64,64) -> 4 subbands (32,32,32,64) each ----
// order: 0=approx(h0,h0) 1=lh(h0,h1) 2=hl(h1,h0) 3=hh(h1,h1)  (H-filter, W-filter)
__global__ __launch_bounds__(256) void k_dwt2(const float* __restrict__ ll1,
                                              float* __restrict__ subs) {
  int tid = blockIdx.x * 256 + threadIdx.x;
  int c  = tid & 63;
  int ow = (tid >> 6) & 31;
  int oh = (tid >> 11) & 31;
  int b  = tid >> 16;
  const float* sb = ll1 + ((size_t)b << 18) + c;  // b*64*64*64
  float a_ll = 0.f, a_lh = 0.f, a_hl = 0.f, a_hh = 0.f;
#pragma unroll
  for (int i = 0; i < 8; ++i) {
    int ih = 2 * oh - 3 + i;
    if ((unsigned)ih < 64u) {
      const float* row = sb + ih * (64 * 64);
      float rl = 0.f, rh = 0.f;
#pragma unroll
      for (int j = 0; j < 8; ++j) {
        int iw = 2 * ow - 3 + j;
        if ((unsigned)iw < 64u) {
          float v = row[iw << 6];
          rl += c_h0[j] * v;
          rh += c_h1[j] * v;
        }
      }
      a_ll += c_h0[i] * rl;
      a_lh += c_h0[i] * rh;
      a_hl += c_h1[i] * rl;
      a_hh += c_h1[i] * rh;
    }
  }
  subs[tid]           = a_ll;
  subs[tid + 2097152] = a_lh;
  subs[tid + 4194304] = a_hl;
  subs[tid + 6291456] = a_hh;
}

// ---- Weight transpose: W[i,o,h,w] (4096 x 1024) -> Wt[hw][io] (1024 x 4096) ----
__global__ __launch_bounds__(256) void k_transpose(const float* __restrict__ w1,
                                                   const float* __restrict__ w2,
                                                   const float* __restrict__ w3,
                                                   const float* __restrict__ w4,
                                                   float* __restrict__ wt) {
  __shared__ float tile[32][33];
  int s = blockIdx.z;
  const float* w = (s == 0) ? w1 : (s == 1) ? w2 : (s == 2) ? w3 : w4;
  int hw0 = blockIdx.x * 32;
  int io0 = blockIdx.y * 32;
  int tx = threadIdx.x & 31;
  int ty = threadIdx.x >> 5;  // 0..7
#pragma unroll
  for (int k = 0; k < 4; ++k) {
    int r = ty + k * 8;
    tile[r][tx] = w[(io0 + r) * 1024 + hw0 + tx];
  }
  __syncthreads();
  float* o = wt + (size_t)s * 4194304;
#pragma unroll
  for (int k = 0; k < 4; ++k) {
    int r = ty + k * 8;
    o[(hw0 + r) * 4096 + io0 + tx] = tile[tx][r];
  }
}

// ---- Einsum: out[b,p,o] = sum_i A[b,p,i] * W[i,o,p], per spatial position p ----
__global__ __launch_bounds__(256) void k_einsum(const float* __restrict__ subs,
                                               const float* __restrict__ w1,
                                               const float* __restrict__ w2,
                                               const float* __restrict__ w3,
                                               const float* __restrict__ w4,
                                               const float* __restrict__ wt,
                                               float* __restrict__ eout,
                                               int use_wt) {
  __shared__ float sW[4096];  // [i][o]
  __shared__ float sA[2048];  // [b][i]
  int p = blockIdx.x;   // 0..1023 = h*32+w
  int s = blockIdx.y;   // subband
  int t = threadIdx.x;
  const float* A = subs + (size_t)s * 2097152;
  if (use_wt) {
    const float* Wp = wt + (size_t)s * 4194304 + (size_t)p * 4096;
#pragma unroll
    for (int k = 0; k < 16; ++k) sW[t + 256 * k] = Wp[t + 256 * k];
  } else {
    const float* Ws = (s == 0) ? w1 : (s == 1) ? w2 : (s == 2) ? w3 : w4;
#pragma unroll
    for (int k = 0; k < 16; ++k) {
      int e = t + 256 * k;
      sW[e] = Ws[e * 1024 + p];
    }
  }
#pragma unroll
  for (int k = 0; k < 8; ++k) {
    int e = t + 256 * k;                       // e = b*64 + i
    sA[e] = A[(e >> 6) * 65536 + (p << 6) + (e & 63)];
  }
  __syncthreads();
  int o  = t & 63;
  int bg = t >> 6;  // 0..3, handles b = bg*8 .. bg*8+7
  float acc[8] = {0.f, 0.f, 0.f, 0.f, 0.f, 0.f, 0.f, 0.f};
  for (int i = 0; i < 64; ++i) {
    float wv = sW[(i << 6) + o];
#pragma unroll
    for (int k = 0; k < 8; ++k) acc[k] += sA[((bg * 8 + k) << 6) + i] * wv;
  }
  float* Oo = eout + (size_t)s * 2097152 + (p << 6) + o;
#pragma unroll
  for (int k = 0; k < 8; ++k) Oo[(bg * 8 + k) * 65536] = acc[k];
}

// ---- Inverse level 2: 4 subbands (32,32,32,64) -> res (32,64,64,64) ----
// res[y,x] = sum_i g0[i]*(sum_j g0[j]*ft + g1[j]*lh) + g1[i]*(sum_j g0[j]*hl + g1[j]*hh)
// taps: m = y/2 + {-1,0,1,2}, i = 2m+3-y (always in [0,8)); same for n/j.
__global__ __launch_bounds__(256) void k_invres(const float* __restrict__ eout,
                                                float* __restrict__ res) {
  int tid = blockIdx.x * 256 + threadIdx.x;
  int c  = tid & 63;
  int xx = (tid >> 6) & 63;
  int y  = (tid >> 12) & 63;
  int b  = tid >> 18;
  int r = y >> 1, q = xx >> 1;
  float acc = 0.f;
#pragma unroll
  for (int dm = -1; dm <= 2; ++dm) {
    int m = r + dm;
    if ((unsigned)m < 32u) {
      int i = 2 * m + 3 - y;
      float rowA = 0.f, rowB = 0.f;
#pragma unroll
      for (int dn = -1; dn <= 2; ++dn) {
        int n = q + dn;
        if ((unsigned)n < 32u) {
          int j = 2 * n + 3 - xx;
          int idx = ((b * 32 + m) * 32 + n) * 64 + c;
          float ft = eout[idx];
          float lh = eout[idx + 2097152];
          float hl = eout[idx + 4194304];
          float hh = eout[idx + 6291456];
          rowA += c_g0[j] * ft + c_g1[j] * lh;
          rowB += c_g0[j] * hl + c_g1[j] * hh;
        }
      }
      acc += c_g0[i] * rowA + c_g1[i] * rowB;
    }
  }
  res[tid] = acc;
}

// ---- Final synthesis: res (32,64,64,64) -> out (32,128,128,64), g0 x g0 ----
// Quad-output: thread covers y in {2r,2r+1}, x in {2q,2q+1}; 16 shared loads.
__global__ __launch_bounds__(256) void k_final(const float* __restrict__ res,
                                               float* __restrict__ out) {
  int tid = blockIdx.x * 256 + threadIdx.x;
  int c = tid & 63;
  int q = (tid >> 6) & 63;
  int r = (tid >> 12) & 63;
  int b = tid >> 18;
  float aee = 0.f, aeo = 0.f, aoe = 0.f, aoo = 0.f;
#pragma unroll
  for (int dm = -1; dm <= 2; ++dm) {
    int m = r + dm;
    if ((unsigned)m < 64u) {
      float wy0 = c_g0[2 * dm + 3];  // y even: i = 2*dm+3
      float wy1 = c_g0[2 * dm + 2];  // y odd:  i = 2*dm+2
      float row0 = 0.f, row1 = 0.f;
#pragma unroll
      for (int dn = -1; dn <= 2; ++dn) {
        int n = q + dn;
        if ((unsigned)n < 64u) {
          float v = res[((b * 64 + m) * 64 + n) * 64 + c];
          row0 += c_g0[2 * dn + 3] * v;  // x even
          row1 += c_g0[2 * dn + 2] * v;  // x odd
        }
      }
      aee += wy0 * row0;
      aeo += wy0 * row1;
      aoe += wy1 * row0;
      aoo += wy1 * row1;
    }
  }
  int y = 2 * r, xx = 2 * q;
  float* ob = out + (((size_t)(b * 128 + y)) * 128 + xx) * 64 + c;
  ob[0]            = aee;
  ob[64]           = aeo;
  ob[128 * 64]     = aoe;
  ob[128 * 64 + 64] = aoo;
}

extern "C" void kernel_launch(void* const* d_in, const int* in_sizes, int n_in,
                              void* d_out, int out_size, void* d_ws, size_t ws_size,
                              hipStream_t stream) {
  (void)in_sizes; (void)n_in; (void)out_size;
  const float* x  = (const float*)d_in[0];
  const float* w1 = (const float*)d_in[1];
  const float* w2 = (const float*)d_in[2];
  const float* w3 = (const float*)d_in[3];
  const float* w4 = (const float*)d_in[4];
  float* out = (float*)d_out;
  float* ws  = (float*)d_ws;

  // Workspace layout (floats):
  //   [0,        8388608)  ll1, later reused as res
  //   [8388608, 16777216)  subs (4 x 2097152)
  //   [16777216,25165824)  eout (4 x 2097152)
  //   [25165824,41943040)  wt (4 x 4194304), optional
  float* ll1  = ws;
  float* subs = ws + 8388608;
  float* eout = ws + 16777216;
  float* res  = ws;  // reuse ll1 (dead after k_dwt2)
  float* wt   = ws + 25165824;
  int use_wt = (ws_size >= (size_t)41943040 * 4) ? 1 : 0;

  k_dwt1<<<32768, 256, 0, stream>>>(x, ll1);
  if (use_wt) k_transpose<<<dim3(32, 128, 4), 256, 0, stream>>>(w1, w2, w3, w4, wt);
  k_dwt2<<<8192, 256, 0, stream>>>(ll1, subs);
  k_einsum<<<dim3(1024, 4), 256, 0, stream>>>(subs, w1, w2, w3, w4, wt, eout, use_wt);
  k_invres<<<32768, 256, 0, stream>>>(eout, res);
  k_final<<<32768, 256, 0, stream>>>(res, out);
}

// Round 2
// 595.142 us; speedup vs baseline: 1.3220x; 1.3220x over previous
//
#include <hip/hip_runtime.h>

// WaveletConv2D: 2-level DWT (8-tap), per-position 64x64 channel mix on the
// 4 level-2 subbands, then 2-level inverse DWT. All fp32.
// R2: sliding-window column kernels — each thread fixes (b, ow, c) and marches
// down the output column keeping the horizontally-filtered row window in
// registers. Cuts per-output global-load instruction count 3-6x (R1 showed
// k_dwt1 VMEM-issue-bound: 514 GB/s, VALUBusy 17%, 64 loads/output).

__constant__ float c_h0[8] = {0.0322231f, -0.01260397f, -0.09921954f, 0.2978578f,
                              0.80373875f, 0.49761867f, -0.02963553f, -0.07576571f};
__constant__ float c_h1[8] = {0.07576571f, -0.02963553f, -0.49761867f, 0.80373875f,
                              -0.2978578f, -0.09921954f, 0.01260397f, 0.0322231f};
// g0 = reverse(h0), g1 = reverse(h1)
__constant__ float c_g0[8] = {-0.07576571f, -0.02963553f, 0.49761867f, 0.80373875f,
                              0.2978578f, -0.09921954f, -0.01260397f, 0.0322231f};
__constant__ float c_g1[8] = {0.0322231f, 0.01260397f, -0.09921954f, -0.2978578f,
                              0.80373875f, -0.49761867f, -0.02963553f, 0.07576571f};

// ---- Stage 1: x (32,128,128,64) -> ll1 (32,64,64,64), h0 x h0, stride 2, pad 3 ----
// Thread: fixed (b, ow, c), 16 output rows (one chunk). Ring of 8 h-filtered rows.
__global__ __launch_bounds__(256) void k_dwt1(const float* __restrict__ x,
                                              float* __restrict__ ll1) {
  int t = threadIdx.x;
  int c = t & 63;
  int owi = t >> 6;                 // 0..3
  int bid = blockIdx.x;             // b*64 + chunk*16 + owg
  int owg = bid & 15;
  int chunk = (bid >> 4) & 3;
  int b = bid >> 6;
  int ow = owg * 4 + owi;
  int oh0 = chunk * 16;
  const float* xb = x + ((size_t)b << 20) + c;
  int iwbase = 2 * ow - 3;

  auto hrow = [&](int ih) -> float {
    if ((unsigned)ih >= 128u) return 0.f;
    const float* row = xb + ih * 8192;
    float r = 0.f;
#pragma unroll
    for (int j = 0; j < 8; ++j) {
      int iw = iwbase + j;
      if ((unsigned)iw < 128u) r += c_h0[j] * row[iw << 6];
    }
    return r;
  };

  float ring[8];
  int ihb = 2 * oh0 - 3;
#pragma unroll
  for (int k = 0; k < 6; ++k) ring[k] = hrow(ihb + k);
  float* outp = ll1 + ((((size_t)b * 64 + oh0) * 64 + ow) << 6) + c;
#pragma unroll
  for (int oo = 0; oo < 16; ++oo) {
    ring[6] = hrow(ihb + 6);
    ring[7] = hrow(ihb + 7);
    float a = 0.f;
#pragma unroll
    for (int i = 0; i < 8; ++i) a += c_h0[i] * ring[i];
    outp[oo * 4096] = a;
#pragma unroll
    for (int k = 0; k < 6; ++k) ring[k] = ring[k + 2];
    ihb += 2;
  }
}

// ---- Stage 2: ll1 (32,64,64,64) -> 4 subbands (32,32,32,64) ----
// Thread: fixed (b, ow, c), 16 output rows. Two rings (h0-row, h1-row).
__global__ __launch_bounds__(256) void k_dwt2(const float* __restrict__ ll1,
                                              float* __restrict__ subs) {
  int t = threadIdx.x;
  int c = t & 63;
  int owi = t >> 6;
  int bid = blockIdx.x;             // b*16 + chunk*8 + owg
  int owg = bid & 7;
  int chunk = (bid >> 3) & 1;
  int b = bid >> 4;
  int ow = owg * 4 + owi;
  int oh0 = chunk * 16;
  const float* sb = ll1 + ((size_t)b << 18) + c;
  int iwbase = 2 * ow - 3;

  float Rl[8], Rh[8];
  auto hrow2 = [&](int ih, float& rl, float& rh) {
    rl = 0.f; rh = 0.f;
    if ((unsigned)ih >= 64u) return;
    const float* row = sb + ih * 4096;
#pragma unroll
    for (int j = 0; j < 8; ++j) {
      int iw = iwbase + j;
      if ((unsigned)iw < 64u) {
        float v = row[iw << 6];
        rl += c_h0[j] * v;
        rh += c_h1[j] * v;
      }
    }
  };

  int ihb = 2 * oh0 - 3;
#pragma unroll
  for (int k = 0; k < 6; ++k) hrow2(ihb + k, Rl[k], Rh[k]);
  float* outp = subs + ((((size_t)b * 32 + oh0) * 32 + ow) << 6) + c;
#pragma unroll
  for (int oo = 0; oo < 16; ++oo) {
    hrow2(ihb + 6, Rl[6], Rh[6]);
    hrow2(ihb + 7, Rl[7], Rh[7]);
    float a_ll = 0.f, a_lh = 0.f, a_hl = 0.f, a_hh = 0.f;
#pragma unroll
    for (int i = 0; i < 8; ++i) {
      a_ll += c_h0[i] * Rl[i];
      a_lh += c_h0[i] * Rh[i];
      a_hl += c_h1[i] * Rl[i];
      a_hh += c_h1[i] * Rh[i];
    }
    float* o = outp + oo * 2048;   // oh stride = 32*64
    o[0]       = a_ll;
    o[2097152] = a_lh;
    o[4194304] = a_hl;
    o[6291456] = a_hh;
#pragma unroll
    for (int k = 0; k < 6; ++k) { Rl[k] = Rl[k + 2]; Rh[k] = Rh[k + 2]; }
    ihb += 2;
  }
}

// ---- Weight transpose: W[i,o,h,w] (4096 x 1024) -> Wt[hw][io] (1024 x 4096) ----
__global__ __launch_bounds__(256) void k_transpose(const float* __restrict__ w1,
                                                   const float* __restrict__ w2,
                                                   const float* __restrict__ w3,
                                                   const float* __restrict__ w4,
                                                   float* __restrict__ wt) {
  __shared__ float tile[32][33];
  int s = blockIdx.z;
  const float* w = (s == 0) ? w1 : (s == 1) ? w2 : (s == 2) ? w3 : w4;
  int hw0 = blockIdx.x * 32;
  int io0 = blockIdx.y * 32;
  int tx = threadIdx.x & 31;
  int ty = threadIdx.x >> 5;  // 0..7
#pragma unroll
  for (int k = 0; k < 4; ++k) {
    int r = ty + k * 8;
    tile[r][tx] = w[(io0 + r) * 1024 + hw0 + tx];
  }
  __syncthreads();
  float* o = wt + (size_t)s * 4194304;
#pragma unroll
  for (int k = 0; k < 4; ++k) {
    int r = ty + k * 8;
    o[(hw0 + r) * 4096 + io0 + tx] = tile[tx][r];
  }
}

// ---- Einsum: out[b,p,o] = sum_i A[b,p,i] * W[i,o,p], per spatial position p ----
__global__ __launch_bounds__(256) void k_einsum(const float* __restrict__ subs,
                                               const float* __restrict__ w1,
                                               const float* __restrict__ w2,
                                               const float* __restrict__ w3,
                                               const float* __restrict__ w4,
                                               const float* __restrict__ wt,
                                               float* __restrict__ eout,
                                               int use_wt) {
  __shared__ float sW[4096];  // [i][o]
  __shared__ float sA[2048];  // [b][i]
  int p = blockIdx.x;   // 0..1023 = h*32+w
  int s = blockIdx.y;   // subband
  int t = threadIdx.x;
  const float* A = subs + (size_t)s * 2097152;
  if (use_wt) {
    const float* Wp = wt + (size_t)s * 4194304 + (size_t)p * 4096;
#pragma unroll
    for (int k = 0; k < 16; ++k) sW[t + 256 * k] = Wp[t + 256 * k];
  } else {
    const float* Ws = (s == 0) ? w1 : (s == 1) ? w2 : (s == 2) ? w3 : w4;
#pragma unroll
    for (int k = 0; k < 16; ++k) {
      int e = t + 256 * k;
      sW[e] = Ws[e * 1024 + p];
    }
  }
#pragma unroll
  for (int k = 0; k < 8; ++k) {
    int e = t + 256 * k;                       // e = b*64 + i
    sA[e] = A[(e >> 6) * 65536 + (p << 6) + (e & 63)];
  }
  __syncthreads();
  int o  = t & 63;
  int bg = t >> 6;  // 0..3, handles b = bg*8 .. bg*8+7
  float acc[8] = {0.f, 0.f, 0.f, 0.f, 0.f, 0.f, 0.f, 0.f};
  for (int i = 0; i < 64; ++i) {
    float wv = sW[(i << 6) + o];
#pragma unroll
    for (int k = 0; k < 8; ++k) acc[k] += sA[((bg * 8 + k) << 6) + i] * wv;
  }
  float* Oo = eout + (size_t)s * 2097152 + (p << 6) + o;
#pragma unroll
  for (int k = 0; k < 8; ++k) Oo[(bg * 8 + k) * 65536] = acc[k];
}

// ---- Inverse level 2: 4 subbands (32,32,32,64) -> res (32,64,64,64) ----
// Thread: fixed (b, q, c) -> x in {2q,2q+1}; loop r -> y in {2r,2r+1}.
// Per r: one new subband row m=r+2 (16 loads), 4 outputs. Rings depth 4.
__global__ __launch_bounds__(256) void k_invres(const float* __restrict__ eout,
                                                float* __restrict__ res) {
  int t = threadIdx.x;
  int c = t & 63;
  int qi = t >> 6;
  int bid = blockIdx.x;             // b*16 + chunk*8 + qg
  int qg = bid & 7;
  int chunk = (bid >> 3) & 1;
  int b = bid >> 4;
  int q = qg * 4 + qi;
  int r0 = chunk * 16;

  float Ae[4], Ao[4], Be[4], Bo[4];
  auto loadrow = [&](int m, float& ae, float& ao, float& be, float& bo) {
    ae = 0.f; ao = 0.f; be = 0.f; bo = 0.f;
    if ((unsigned)m >= 32u) return;
#pragma unroll
    for (int dn = -1; dn <= 2; ++dn) {
      int n = q + dn;
      if ((unsigned)n < 32u) {
        int idx = ((b * 32 + m) * 32 + n) * 64 + c;
        float ft = eout[idx];
        float lh = eout[idx + 2097152];
        float hl = eout[idx + 4194304];
        float hh = eout[idx + 6291456];
        float g0e = c_g0[2 * dn + 3], g1e = c_g1[2 * dn + 3];  // x even
        float g0o = c_g0[2 * dn + 2], g1o = c_g1[2 * dn + 2];  // x odd
        ae += g0e * ft + g1e * lh;
        ao += g0o * ft + g1o * lh;
        be += g0e * hl + g1e * hh;
        bo += g0o * hl + g1o * hh;
      }
    }
  };

#pragma unroll
  for (int k = 0; k < 3; ++k) loadrow(r0 - 1 + k, Ae[k], Ao[k], Be[k], Bo[k]);
#pragma unroll
  for (int rr = 0; rr < 16; ++rr) {
    int r = r0 + rr;
    loadrow(r + 2, Ae[3], Ao[3], Be[3], Bo[3]);
    float ee = 0.f, eo = 0.f, oe = 0.f, oo = 0.f;
#pragma unroll
    for (int dm = 0; dm < 4; ++dm) {
      float gye = c_g0[2 * dm + 1];   // y even: i = 2*(dm-1)+3
      float hye = c_g1[2 * dm + 1];
      float gyo = c_g0[2 * dm];       // y odd:  i = 2*(dm-1)+2
      float hyo = c_g1[2 * dm];
      ee += gye * Ae[dm] + hye * Be[dm];
      eo += gye * Ao[dm] + hye * Bo[dm];
      oe += gyo * Ae[dm] + hyo * Be[dm];
      oo += gyo * Ao[dm] + hyo * Bo[dm];
    }
    int y = 2 * r, xx = 2 * q;
    float* ob = res + (((size_t)(b * 64 + y)) * 64 + xx) * 64 + c;
    ob[0]           = ee;
    ob[64]          = eo;
    ob[64 * 64]     = oe;
    ob[64 * 64 + 64] = oo;
#pragma unroll
    for (int k = 0; k < 3; ++k) { Ae[k] = Ae[k + 1]; Ao[k] = Ao[k + 1]; Be[k] = Be[k + 1]; Bo[k] = Bo[k + 1]; }
  }
}

// ---- Final synthesis: res (32,64,64,64) -> out (32,128,128,64), g0 x g0 ----
// Thread: fixed (b, q, c) -> x in {2q,2q+1}; loop r; 1 new row (4 loads) per 4 outputs.
__global__ __launch_bounds__(256) void k_final(const float* __restrict__ res,
                                               float* __restrict__ out) {
  int t = threadIdx.x;
  int c = t & 63;
  int qi = t >> 6;
  int bid = blockIdx.x;             // b*64 + chunk*16 + qg
  int qg = bid & 15;
  int chunk = (bid >> 4) & 3;
  int b = bid >> 6;
  int q = qg * 4 + qi;
  int r0 = chunk * 16;

  float R0[4], R1[4];
  auto loadrow = [&](int m, float& row0, float& row1) {
    row0 = 0.f; row1 = 0.f;
    if ((unsigned)m >= 64u) return;
#pragma unroll
    for (int dn = -1; dn <= 2; ++dn) {
      int n = q + dn;
      if ((unsigned)n < 64u) {
        float v = res[(((size_t)(b * 64 + m)) * 64 + n) * 64 + c];
        row0 += c_g0[2 * dn + 3] * v;
        row1 += c_g0[2 * dn + 2] * v;
      }
    }
  };

#pragma unroll
  for (int k = 0; k < 3; ++k) loadrow(r0 - 1 + k, R0[k], R1[k]);
#pragma unroll
  for (int rr = 0; rr < 16; ++rr) {
    int r = r0 + rr;
    loadrow(r + 2, R0[3], R1[3]);
    float aee = 0.f, aeo = 0.f, aoe = 0.f, aoo = 0.f;
#pragma unroll
    for (int dm = 0; dm < 4; ++dm) {
      float gye = c_g0[2 * dm + 1];
      float gyo = c_g0[2 * dm];
      aee += gye * R0[dm];
      aeo += gye * R1[dm];
      aoe += gyo * R0[dm];
      aoo += gyo * R1[dm];
    }
    int y = 2 * r, xx = 2 * q;
    float* ob = out + (((size_t)(b * 128 + y)) * 128 + xx) * 64 + c;
    ob[0]             = aee;
    ob[64]            = aeo;
    ob[128 * 64]      = aoe;
    ob[128 * 64 + 64] = aoo;
#pragma unroll
    for (int k = 0; k < 3; ++k) { R0[k] = R0[k + 1]; R1[k] = R1[k + 1]; }
  }
}

extern "C" void kernel_launch(void* const* d_in, const int* in_sizes, int n_in,
                              void* d_out, int out_size, void* d_ws, size_t ws_size,
                              hipStream_t stream) {
  (void)in_sizes; (void)n_in; (void)out_size;
  const float* x  = (const float*)d_in[0];
  const float* w1 = (const float*)d_in[1];
  const float* w2 = (const float*)d_in[2];
  const float* w3 = (const float*)d_in[3];
  const float* w4 = (const float*)d_in[4];
  float* out = (float*)d_out;
  float* ws  = (float*)d_ws;

  // Workspace layout (floats):
  //   [0,        8388608)  ll1, later reused as res
  //   [8388608, 16777216)  subs (4 x 2097152)
  //   [16777216,25165824)  eout (4 x 2097152)
  //   [25165824,41943040)  wt (4 x 4194304), optional
  float* ll1  = ws;
  float* subs = ws + 8388608;
  float* eout = ws + 16777216;
  float* res  = ws;  // reuse ll1 (dead after k_dwt2)
  float* wt   = ws + 25165824;
  int use_wt = (ws_size >= (size_t)41943040 * 4) ? 1 : 0;

  k_dwt1<<<2048, 256, 0, stream>>>(x, ll1);
  if (use_wt) k_transpose<<<dim3(32, 128, 4), 256, 0, stream>>>(w1, w2, w3, w4, wt);
  k_dwt2<<<512, 256, 0, stream>>>(ll1, subs);
  k_einsum<<<dim3(1024, 4), 256, 0, stream>>>(subs, w1, w2, w3, w4, wt, eout, use_wt);
  k_invres<<<512, 256, 0, stream>>>(eout, res);
  k_final<<<2048, 256, 0, stream>>>(res, out);
}

// Round 3
// 385.981 us; speedup vs baseline: 2.0383x; 1.5419x over previous
//
#include <hip/hip_runtime.h>

// WaveletConv2D: 2-level DWT (8-tap), per-position 64x64 channel mix on the
// 4 level-2 subbands, then 2-level inverse DWT. All fp32.
// R3: float4 channel-grouping (lane = 16 c-groups x 4 spatial). R2 showed
// VGPR=16 -> serialized scalar loads (~40 cyc/load-instr). Batching 8-16
// float4 loads into register arrays restores MLP and cuts VMEM instrs 4x.

__constant__ float c_h0[8] = {0.0322231f, -0.01260397f, -0.09921954f, 0.2978578f,
                              0.80373875f, 0.49761867f, -0.02963553f, -0.07576571f};
__constant__ float c_h1[8] = {0.07576571f, -0.02963553f, -0.49761867f, 0.80373875f,
                              -0.2978578f, -0.09921954f, 0.01260397f, 0.0322231f};
// g0 = reverse(h0), g1 = reverse(h1)
__constant__ float c_g0[8] = {-0.07576571f, -0.02963553f, 0.49761867f, 0.80373875f,
                              0.2978578f, -0.09921954f, -0.01260397f, 0.0322231f};
__constant__ float c_g1[8] = {0.0322231f, 0.01260397f, -0.09921954f, -0.2978578f,
                              0.80373875f, -0.49761867f, -0.02963553f, 0.07576571f};

__device__ __forceinline__ float4 f4z() { return make_float4(0.f, 0.f, 0.f, 0.f); }
__device__ __forceinline__ float4 f4fma(float4 a, float w, float4 v) {
  a.x = fmaf(w, v.x, a.x); a.y = fmaf(w, v.y, a.y);
  a.z = fmaf(w, v.z, a.z); a.w = fmaf(w, v.w, a.w);
  return a;
}

// ---- Stage 1: x (32,128,128,64) -> ll1 (32,64,64,64), h0 x h0, stride 2, pad 3 ----
// Thread: (b, ow, c4) marching 16 output rows. Ring of 8 h-filtered float4 rows.
__global__ __launch_bounds__(256) void k_dwt1(const float* __restrict__ x,
                                              float* __restrict__ ll1) {
  int t = threadIdx.x;
  int c4 = t & 15;
  int owl = t >> 4;                 // 0..15
  int bid = blockIdx.x;             // b*16 + ohc*4 + owb
  int owb = bid & 3;
  int ohc = (bid >> 2) & 3;
  int b   = bid >> 4;
  int ow  = owb * 16 + owl;
  int oh0 = ohc * 16;
  const float* xb = x + ((size_t)b << 20) + (c4 << 2);
  int iwbase = 2 * ow - 3;

  auto hrow = [&](int ih) -> float4 {
    float4 r = f4z();
    if ((unsigned)ih >= 128u) return r;
    const float* row = xb + ih * 8192;
    float4 v[8];
#pragma unroll
    for (int j = 0; j < 8; ++j) {
      int iw = iwbase + j;
      int iwc = min(max(iw, 0), 127);
      v[j] = *(const float4*)(row + (iwc << 6));
    }
#pragma unroll
    for (int j = 0; j < 8; ++j) {
      int iw = iwbase + j;
      float w = ((unsigned)iw < 128u) ? c_h0[j] : 0.f;
      r = f4fma(r, w, v[j]);
    }
    return r;
  };

  float4 ring[8];
  int ihb = 2 * oh0 - 3;
#pragma unroll
  for (int k = 0; k < 6; ++k) ring[k] = hrow(ihb + k);
  float* outp = ll1 + ((((size_t)b * 64 + oh0) * 64 + ow) << 6) + (c4 << 2);
#pragma unroll
  for (int oo = 0; oo < 16; ++oo) {
    ring[6] = hrow(ihb + 6);
    ring[7] = hrow(ihb + 7);
    float4 a = f4z();
#pragma unroll
    for (int i = 0; i < 8; ++i) a = f4fma(a, c_h0[i], ring[i]);
    *(float4*)(outp + oo * 4096) = a;
#pragma unroll
    for (int k = 0; k < 6; ++k) ring[k] = ring[k + 2];
    ihb += 2;
  }
}

// ---- Stage 2: ll1 (32,64,64,64) -> 4 subbands (32,32,32,64) ----
__global__ __launch_bounds__(256) void k_dwt2(const float* __restrict__ ll1,
                                              float* __restrict__ subs) {
  int t = threadIdx.x;
  int c4 = t & 15;
  int owl = t >> 4;
  int bid = blockIdx.x;             // b*8 + ohc*2 + owb
  int owb = bid & 1;
  int ohc = (bid >> 1) & 3;
  int b   = bid >> 3;
  int ow  = owb * 16 + owl;
  int oh0 = ohc * 8;
  const float* sb = ll1 + ((size_t)b << 18) + (c4 << 2);
  int iwbase = 2 * ow - 3;

  auto hrow2 = [&](int ih, float4& rl, float4& rh) {
    rl = f4z(); rh = f4z();
    if ((unsigned)ih >= 64u) return;
    const float* row = sb + ih * 4096;
    float4 v[8];
#pragma unroll
    for (int j = 0; j < 8; ++j) {
      int iw = iwbase + j;
      int iwc = min(max(iw, 0), 63);
      v[j] = *(const float4*)(row + (iwc << 6));
    }
#pragma unroll
    for (int j = 0; j < 8; ++j) {
      int iw = iwbase + j;
      bool ok = (unsigned)iw < 64u;
      float wl = ok ? c_h0[j] : 0.f;
      float wh = ok ? c_h1[j] : 0.f;
      rl = f4fma(rl, wl, v[j]);
      rh = f4fma(rh, wh, v[j]);
    }
  };

  float4 Rl[8], Rh[8];
  int ihb = 2 * oh0 - 3;
#pragma unroll
  for (int k = 0; k < 6; ++k) hrow2(ihb + k, Rl[k], Rh[k]);
  float* outp = subs + ((((size_t)b * 32 + oh0) * 32 + ow) << 6) + (c4 << 2);
#pragma unroll
  for (int oo = 0; oo < 8; ++oo) {
    hrow2(ihb + 6, Rl[6], Rh[6]);
    hrow2(ihb + 7, Rl[7], Rh[7]);
    float4 a_ll = f4z(), a_lh = f4z(), a_hl = f4z(), a_hh = f4z();
#pragma unroll
    for (int i = 0; i < 8; ++i) {
      a_ll = f4fma(a_ll, c_h0[i], Rl[i]);
      a_lh = f4fma(a_lh, c_h0[i], Rh[i]);
      a_hl = f4fma(a_hl, c_h1[i], Rl[i]);
      a_hh = f4fma(a_hh, c_h1[i], Rh[i]);
    }
    float* o = outp + oo * 2048;
    *(float4*)(o)           = a_ll;
    *(float4*)(o + 2097152) = a_lh;
    *(float4*)(o + 4194304) = a_hl;
    *(float4*)(o + 6291456) = a_hh;
#pragma unroll
    for (int k = 0; k < 6; ++k) { Rl[k] = Rl[k + 2]; Rh[k] = Rh[k + 2]; }
    ihb += 2;
  }
}

// ---- Weight transpose: W[i,o,h,w] (4096 x 1024) -> Wt[hw][io] (1024 x 4096) ----
__global__ __launch_bounds__(256) void k_transpose(const float* __restrict__ w1,
                                                   const float* __restrict__ w2,
                                                   const float* __restrict__ w3,
                                                   const float* __restrict__ w4,
                                                   float* __restrict__ wt) {
  __shared__ float tile[32][33];
  int s = blockIdx.z;
  const float* w = (s == 0) ? w1 : (s == 1) ? w2 : (s == 2) ? w3 : w4;
  int hw0 = blockIdx.x * 32;
  int io0 = blockIdx.y * 32;
  int tx = threadIdx.x & 31;
  int ty = threadIdx.x >> 5;  // 0..7
#pragma unroll
  for (int k = 0; k < 4; ++k) {
    int r = ty + k * 8;
    tile[r][tx] = w[(io0 + r) * 1024 + hw0 + tx];
  }
  __syncthreads();
  float* o = wt + (size_t)s * 4194304;
#pragma unroll
  for (int k = 0; k < 4; ++k) {
    int r = ty + k * 8;
    o[(hw0 + r) * 4096 + io0 + tx] = tile[tx][r];
  }
}

// ---- Einsum: out[b,p,o] = sum_i A[b,p,i] * W[i,o,p], per spatial position p ----
__global__ __launch_bounds__(256) void k_einsum(const float* __restrict__ subs,
                                               const float* __restrict__ w1,
                                               const float* __restrict__ w2,
                                               const float* __restrict__ w3,
                                               const float* __restrict__ w4,
                                               const float* __restrict__ wt,
                                               float* __restrict__ eout,
                                               int use_wt) {
  __shared__ float sW[4096];  // [i][o]
  __shared__ float sA[2048];  // [b][i]
  int p = blockIdx.x;   // 0..1023 = h*32+w
  int s = blockIdx.y;   // subband
  int t = threadIdx.x;
  const float* A = subs + (size_t)s * 2097152;
  if (use_wt) {
    const float* Wp = wt + (size_t)s * 4194304 + (size_t)p * 4096;
#pragma unroll
    for (int k = 0; k < 16; ++k) sW[t + 256 * k] = Wp[t + 256 * k];
  } else {
    const float* Ws = (s == 0) ? w1 : (s == 1) ? w2 : (s == 2) ? w3 : w4;
#pragma unroll
    for (int k = 0; k < 16; ++k) {
      int e = t + 256 * k;
      sW[e] = Ws[e * 1024 + p];
    }
  }
#pragma unroll
  for (int k = 0; k < 8; ++k) {
    int e = t + 256 * k;                       // e = b*64 + i
    sA[e] = A[(e >> 6) * 65536 + (p << 6) + (e & 63)];
  }
  __syncthreads();
  int o  = t & 63;
  int bg = t >> 6;  // 0..3, handles b = bg*8 .. bg*8+7
  float acc[8] = {0.f, 0.f, 0.f, 0.f, 0.f, 0.f, 0.f, 0.f};
  for (int i = 0; i < 64; ++i) {
    float wv = sW[(i << 6) + o];
#pragma unroll
    for (int k = 0; k < 8; ++k) acc[k] += sA[((bg * 8 + k) << 6) + i] * wv;
  }
  float* Oo = eout + (size_t)s * 2097152 + (p << 6) + o;
#pragma unroll
  for (int k = 0; k < 8; ++k) Oo[(bg * 8 + k) * 65536] = acc[k];
}

// ---- Inverse level 2: 4 subbands (32,32,32,64) -> res (32,64,64,64) ----
// Thread: (b, q, c4) -> x in {2q,2q+1}; loop r -> y in {2r,2r+1}. Rings depth 4.
__global__ __launch_bounds__(256) void k_invres(const float* __restrict__ eout,
                                                float* __restrict__ res) {
  int t = threadIdx.x;
  int c4 = t & 15;
  int ql = t >> 4;
  int bid = blockIdx.x;             // b*8 + rc*2 + qb
  int qb = bid & 1;
  int rc = (bid >> 1) & 3;
  int b  = bid >> 3;
  int q  = qb * 16 + ql;
  int r0 = rc * 8;

  float4 Ae[4], Ao[4], Be[4], Bo[4];
  auto loadrow = [&](int m, float4& ae, float4& ao, float4& be, float4& bo) {
    ae = f4z(); ao = f4z(); be = f4z(); bo = f4z();
    if ((unsigned)m >= 32u) return;
    const float* base = eout + ((((size_t)b * 32 + m) * 32) << 6) + (c4 << 2);
    float4 vf[4], vl[4], vh[4], vv[4];
#pragma unroll
    for (int dn = -1; dn <= 2; ++dn) {
      int n = q + dn;
      int nc = min(max(n, 0), 31);
      const float* p = base + (nc << 6);
      vf[dn + 1] = *(const float4*)(p);
      vl[dn + 1] = *(const float4*)(p + 2097152);
      vh[dn + 1] = *(const float4*)(p + 4194304);
      vv[dn + 1] = *(const float4*)(p + 6291456);
    }
#pragma unroll
    for (int dn = -1; dn <= 2; ++dn) {
      int n = q + dn;
      bool ok = (unsigned)n < 32u;
      float g0e = ok ? c_g0[2 * dn + 3] : 0.f, g1e = ok ? c_g1[2 * dn + 3] : 0.f;
      float g0o = ok ? c_g0[2 * dn + 2] : 0.f, g1o = ok ? c_g1[2 * dn + 2] : 0.f;
      ae = f4fma(ae, g0e, vf[dn + 1]); ae = f4fma(ae, g1e, vl[dn + 1]);
      ao = f4fma(ao, g0o, vf[dn + 1]); ao = f4fma(ao, g1o, vl[dn + 1]);
      be = f4fma(be, g0e, vh[dn + 1]); be = f4fma(be, g1e, vv[dn + 1]);
      bo = f4fma(bo, g0o, vh[dn + 1]); bo = f4fma(bo, g1o, vv[dn + 1]);
    }
  };

#pragma unroll
  for (int k = 0; k < 3; ++k) loadrow(r0 - 1 + k, Ae[k], Ao[k], Be[k], Bo[k]);
#pragma unroll
  for (int rr = 0; rr < 8; ++rr) {
    int r = r0 + rr;
    loadrow(r + 2, Ae[3], Ao[3], Be[3], Bo[3]);
    float4 ee = f4z(), eo = f4z(), oe = f4z(), oo = f4z();
#pragma unroll
    for (int dm = 0; dm < 4; ++dm) {
      float gye = c_g0[2 * dm + 1], hye = c_g1[2 * dm + 1];
      float gyo = c_g0[2 * dm],     hyo = c_g1[2 * dm];
      ee = f4fma(ee, gye, Ae[dm]); ee = f4fma(ee, hye, Be[dm]);
      eo = f4fma(eo, gye, Ao[dm]); eo = f4fma(eo, hye, Bo[dm]);
      oe = f4fma(oe, gyo, Ae[dm]); oe = f4fma(oe, hyo, Be[dm]);
      oo = f4fma(oo, gyo, Ao[dm]); oo = f4fma(oo, hyo, Bo[dm]);
    }
    int y = 2 * r, xx = 2 * q;
    float* ob = res + (((size_t)(b * 64 + y)) * 64 + xx) * 64 + (c4 << 2);
    *(float4*)(ob)                = ee;
    *(float4*)(ob + 64)           = eo;
    *(float4*)(ob + 4096)         = oe;
    *(float4*)(ob + 4096 + 64)    = oo;
#pragma unroll
    for (int k = 0; k < 3; ++k) {
      Ae[k] = Ae[k + 1]; Ao[k] = Ao[k + 1]; Be[k] = Be[k + 1]; Bo[k] = Bo[k + 1];
    }
  }
}

// ---- Final synthesis: res (32,64,64,64) -> out (32,128,128,64), g0 x g0 ----
__global__ __launch_bounds__(256) void k_final(const float* __restrict__ res,
                                               float* __restrict__ out) {
  int t = threadIdx.x;
  int c4 = t & 15;
  int ql = t >> 4;
  int bid = blockIdx.x;             // b*16 + rc*4 + qb
  int qb = bid & 3;
  int rc = (bid >> 2) & 3;
  int b  = bid >> 4;
  int q  = qb * 16 + ql;
  int r0 = rc * 16;

  float4 R0[4], R1[4];
  auto loadrow = [&](int m, float4& row0, float4& row1) {
    row0 = f4z(); row1 = f4z();
    if ((unsigned)m >= 64u) return;
    const float* base = res + (((size_t)(b * 64 + m)) * 64) * 64 + (c4 << 2);
    float4 v[4];
#pragma unroll
    for (int dn = -1; dn <= 2; ++dn) {
      int n = q + dn;
      int nc = min(max(n, 0), 63);
      v[dn + 1] = *(const float4*)(base + (nc << 6));
    }
#pragma unroll
    for (int dn = -1; dn <= 2; ++dn) {
      int n = q + dn;
      bool ok = (unsigned)n < 64u;
      float we = ok ? c_g0[2 * dn + 3] : 0.f;
      float wo = ok ? c_g0[2 * dn + 2] : 0.f;
      row0 = f4fma(row0, we, v[dn + 1]);
      row1 = f4fma(row1, wo, v[dn + 1]);
    }
  };

#pragma unroll
  for (int k = 0; k < 3; ++k) loadrow(r0 - 1 + k, R0[k], R1[k]);
#pragma unroll
  for (int rr = 0; rr < 16; ++rr) {
    int r = r0 + rr;
    loadrow(r + 2, R0[3], R1[3]);
    float4 aee = f4z(), aeo = f4z(), aoe = f4z(), aoo = f4z();
#pragma unroll
    for (int dm = 0; dm < 4; ++dm) {
      float gye = c_g0[2 * dm + 1];
      float gyo = c_g0[2 * dm];
      aee = f4fma(aee, gye, R0[dm]);
      aeo = f4fma(aeo, gye, R1[dm]);
      aoe = f4fma(aoe, gyo, R0[dm]);
      aoo = f4fma(aoo, gyo, R1[dm]);
    }
    int y = 2 * r, xx = 2 * q;
    float* ob = out + (((size_t)(b * 128 + y)) * 128 + xx) * 64 + (c4 << 2);
    *(float4*)(ob)                 = aee;
    *(float4*)(ob + 64)            = aeo;
    *(float4*)(ob + 8192)          = aoe;
    *(float4*)(ob + 8192 + 64)     = aoo;
#pragma unroll
    for (int k = 0; k < 3; ++k) { R0[k] = R0[k + 1]; R1[k] = R1[k + 1]; }
  }
}

extern "C" void kernel_launch(void* const* d_in, const int* in_sizes, int n_in,
                              void* d_out, int out_size, void* d_ws, size_t ws_size,
                              hipStream_t stream) {
  (void)in_sizes; (void)n_in; (void)out_size;
  const float* x  = (const float*)d_in[0];
  const float* w1 = (const float*)d_in[1];
  const float* w2 = (const float*)d_in[2];
  const float* w3 = (const float*)d_in[3];
  const float* w4 = (const float*)d_in[4];
  float* out = (float*)d_out;
  float* ws  = (float*)d_ws;

  // Workspace layout (floats):
  //   [0,        8388608)  ll1, later reused as res
  //   [8388608, 16777216)  subs (4 x 2097152)
  //   [16777216,25165824)  eout (4 x 2097152)
  //   [25165824,41943040)  wt (4 x 4194304), optional
  float* ll1  = ws;
  float* subs = ws + 8388608;
  float* eout = ws + 16777216;
  float* res  = ws;  // reuse ll1 (dead after k_dwt2)
  float* wt   = ws + 25165824;
  int use_wt = (ws_size >= (size_t)41943040 * 4) ? 1 : 0;

  k_dwt1<<<512, 256, 0, stream>>>(x, ll1);
  if (use_wt) k_transpose<<<dim3(32, 128, 4), 256, 0, stream>>>(w1, w2, w3, w4, wt);
  k_dwt2<<<256, 256, 0, stream>>>(ll1, subs);
  k_einsum<<<dim3(1024, 4), 256, 0, stream>>>(subs, w1, w2, w3, w4, wt, eout, use_wt);
  k_invres<<<256, 256, 0, stream>>>(eout, res);
  k_final<<<512, 256, 0, stream>>>(res, out);
}